// Round 10
// baseline (165.101 us; speedup 1.0000x reference)
//
#include <hip/hip_runtime.h>
#include <stdint.h>

#define ALPHA 0.2f

typedef __attribute__((ext_vector_type(8))) short bf16x8;
typedef __attribute__((ext_vector_type(8))) unsigned short u16x8;
typedef __attribute__((ext_vector_type(4))) float f32x4;

__device__ __forceinline__ unsigned short f2bf(float f) {
    unsigned int u = __float_as_uint(f);
    u += 0x7fffu + ((u >> 16) & 1u);   // RNE
    return (unsigned short)(u >> 16);
}

__device__ __forceinline__ void gload_lds16(const void* g, void* l) {
    __builtin_amdgcn_global_load_lds(
        (const __attribute__((address_space(1))) unsigned int*)g,
        (__attribute__((address_space(3))) unsigned int*)l, 16, 0, 0);
}

// ---------------------------------------------------------------------------
// Blocks 0..255: Wtbf[o*256+t] = bf16(W[t*256+o]).
// Block 256:     wa[k] = W[k,:]·a_l ; wa[256+k] = W[k,:]·a_r  (fp32).
// ---------------------------------------------------------------------------
__global__ void wt_wa_kernel(const float* __restrict__ W,
                             const float* __restrict__ a,
                             unsigned short* __restrict__ Wtbf,
                             float* __restrict__ wa) {
    const int t = threadIdx.x;
    if (blockIdx.x < 256) {
        const int o = blockIdx.x;
        Wtbf[o * 256 + t] = f2bf(W[t * 256 + o]);
    } else {
        float sl = 0.f, sr = 0.f;
        const float* wr = W + t * 256;
        for (int o = 0; o < 256; ++o) {
            const float wv = wr[o];
            sl += wv * a[o];
            sr += wv * a[256 + o];
        }
        wa[t] = sl;
        wa[256 + t] = sr;
    }
}

// ---------------------------------------------------------------------------
// gemm_hx (R9-verified): h_T (256 x 16384) = Wtbf @ x^T, reading x fp32
// directly; A-panel staged once (XOR-swizzled), barrier-free K-loop;
// blocks y==0 waves 0/1 also produce EXACT fp32 el/er.
// Grid (128, 4) = 512 blocks (2/CU).
// ---------------------------------------------------------------------------
__global__ __launch_bounds__(256) void gemm_hx(
    const unsigned short* __restrict__ Wtbf,   // 256 x 256 bf16
    const float* __restrict__ x,               // 16384 x 256 fp32
    const float* __restrict__ wa,              // 512 fp32
    unsigned short* __restrict__ hT,           // 256 x 16384 bf16
    float* __restrict__ el, float* __restrict__ er)
{
    __shared__ __align__(16) unsigned short As[64 * 256];   // 32 KB (swizzled)
    __shared__ float wa_s[512];

    const int tid = threadIdx.x;
    const int w = tid >> 6, l = tid & 63;
    const int q = l >> 4, ml = l & 15;
    const int wm = (w >> 1) * 32;
    const int wn = (w & 1) * 64;
    const int m0 = blockIdx.y * 64;
    const int n0 = blockIdx.x * 128;

    if (tid < 128) *(float4*)(wa_s + tid * 4) = *(const float4*)(wa + tid * 4);

    for (int rd = 0; rd < 8; ++rd) {
        const int cb = rd * 256 + (w << 6);
        const int p = cb + l;
        const int r = p >> 5;
        const int c = p & 31;
        gload_lds16(Wtbf + (size_t)(m0 + r) * 256 + ((c ^ (r & 7)) << 3),
                    As + cb * 8);
    }
    __syncthreads();

    const bool do_e = (blockIdx.y == 0) && (w < 2);

    f32x4 acc[2][4];
    for (int i = 0; i < 2; ++i)
        for (int j = 0; j < 4; ++j) {
            f32x4 z = {0.f, 0.f, 0.f, 0.f};
            acc[i][j] = z;
        }
    float sl[4] = {0.f, 0.f, 0.f, 0.f};
    float sr[4] = {0.f, 0.f, 0.f, 0.f};

    for (int k0 = 0; k0 < 256; k0 += 64) {
        bf16x8 aF[2][2], bF[2][4];
#pragma unroll
        for (int ks = 0; ks < 2; ++ks) {
            const int kb = k0 + ks * 32 + q * 8;
#pragma unroll
            for (int mt = 0; mt < 2; ++mt) {
                const int row = wm + mt * 16 + ml;
                const int cf = (kb >> 3) ^ (row & 7);
                aF[ks][mt] = *(const bf16x8*)(As + (row * 32 + cf) * 8);
            }
#pragma unroll
            for (int nt = 0; nt < 4; ++nt) {
                const int grow = n0 + wn + nt * 16 + ml;
                const float* xp = x + (size_t)grow * 256 + kb;
                const float4 v0 = *(const float4*)(xp);
                const float4 v1 = *(const float4*)(xp + 4);
                bf16x8 f;
                f[0] = (short)f2bf(v0.x); f[1] = (short)f2bf(v0.y);
                f[2] = (short)f2bf(v0.z); f[3] = (short)f2bf(v0.w);
                f[4] = (short)f2bf(v1.x); f[5] = (short)f2bf(v1.y);
                f[6] = (short)f2bf(v1.z); f[7] = (short)f2bf(v1.w);
                bF[ks][nt] = f;
                if (do_e) {
                    const float* wl = wa_s + kb;
                    const float* wrr = wa_s + 256 + kb;
                    sl[nt] += v0.x * wl[0] + v0.y * wl[1] + v0.z * wl[2] + v0.w * wl[3]
                            + v1.x * wl[4] + v1.y * wl[5] + v1.z * wl[6] + v1.w * wl[7];
                    sr[nt] += v0.x * wrr[0] + v0.y * wrr[1] + v0.z * wrr[2] + v0.w * wrr[3]
                            + v1.x * wrr[4] + v1.y * wrr[5] + v1.z * wrr[6] + v1.w * wrr[7];
                }
            }
        }
#pragma unroll
        for (int ks = 0; ks < 2; ++ks)
            for (int mt = 0; mt < 2; ++mt)
                for (int nt = 0; nt < 4; ++nt)
                    acc[mt][nt] = __builtin_amdgcn_mfma_f32_16x16x32_bf16(
                        aF[ks][mt], bF[ks][nt], acc[mt][nt], 0, 0, 0);
    }

    if (do_e) {
#pragma unroll
        for (int nt = 0; nt < 4; ++nt) {
            sl[nt] += __shfl_xor(sl[nt], 16); sl[nt] += __shfl_xor(sl[nt], 32);
            sr[nt] += __shfl_xor(sr[nt], 16); sr[nt] += __shfl_xor(sr[nt], 32);
        }
        if (l < 16) {
#pragma unroll
            for (int nt = 0; nt < 4; ++nt) {
                const int n = n0 + wn + nt * 16 + l;
                el[n] = sl[nt];
                er[n] = sr[nt];
            }
        }
    }

    for (int mt = 0; mt < 2; ++mt)
        for (int nt = 0; nt < 4; ++nt) {
            const int gn = n0 + wn + nt * 16 + ml;
            for (int r = 0; r < 4; ++r) {
                const int gm = m0 + wm + mt * 16 + q * 4 + r;
                hT[(size_t)gm * 16384 + gn] = f2bf(acc[mt][nt][r]);
            }
        }
}

// ---------------------------------------------------------------------------
// Mask pre-pass (R8-verified): one wave per row, 4096 blocks, ONLINE sum
// (no max pass — logits tiny by construction; exp can't overflow in fp32).
// c[row] = log( sum_j adj ? exp(leakyrelu(el_i+er_j)) : 0 ).
// Adjacency packed to pk16[row*64 + l] (bit t <-> j = 16*l + t).
// ---------------------------------------------------------------------------
__global__ __launch_bounds__(256) void mask_kernel(
    const int* __restrict__ adj,
    const float* __restrict__ el,
    const float* __restrict__ er,
    float* __restrict__ c,
    unsigned short* __restrict__ pk16)
{
    __shared__ unsigned char nibs[4][256];

    const int w = threadIdx.x >> 6, l = threadIdx.x & 63;
    const int row = blockIdx.x * 4 + w;       // 0..16383
    const int b = row >> 10;
    const int* arow = adj + (size_t)row * 1024;
    const float* erb = er + (b << 10);
    const float eli = el[row];

    int4 av[4]; float4 erv[4];
#pragma unroll
    for (int it = 0; it < 4; ++it) {
        const int j = it * 256 + l * 4;
        av[it]  = *(const int4*)(arow + j);
        erv[it] = *(const float4*)(erb + j);
    }

    const float NINF = -__builtin_inff();
    float s = 0.f;
#pragma unroll
    for (int it = 0; it < 4; ++it) {
        float e0 = eli + erv[it].x; e0 = e0 > 0.f ? e0 : ALPHA * e0;
        float e1 = eli + erv[it].y; e1 = e1 > 0.f ? e1 : ALPHA * e1;
        float e2 = eli + erv[it].z; e2 = e2 > 0.f ? e2 : ALPHA * e2;
        float e3 = eli + erv[it].w; e3 = e3 > 0.f ? e3 : ALPHA * e3;
        e0 = av[it].x > 0 ? e0 : NINF;   // exp(-inf) = 0
        e1 = av[it].y > 0 ? e1 : NINF;
        e2 = av[it].z > 0 ? e2 : NINF;
        e3 = av[it].w > 0 ? e3 : NINF;
        s += __expf(e0) + __expf(e1) + __expf(e2) + __expf(e3);
        nibs[w][it * 64 + l] =
            (unsigned char)((av[it].x > 0) | ((av[it].y > 0) << 1) |
                            ((av[it].z > 0) << 2) | ((av[it].w > 0) << 3));
    }
#pragma unroll
    for (int off = 32; off >= 1; off >>= 1) s += __shfl_xor(s, off);
    if (l == 0) c[row] = __logf(s);

    const unsigned nr = *(const unsigned int*)(&nibs[w][l * 4]);
    const unsigned short mask16 =
        (unsigned short)((nr & 0xFu) | ((nr >> 4) & 0xF0u) |
                         ((nr >> 8) & 0xF00u) | ((nr >> 12) & 0xF000u));
    pk16[(size_t)row * 64 + l] = mask16;
}

// ---------------------------------------------------------------------------
// PV (R6-verified): out[b, i0..i0+31, :] = P @ h[b].  Grid (32,16) = 512.
// j-step 64; Hs XOR-swizzled; Ps stride 72.
// ---------------------------------------------------------------------------
__global__ __launch_bounds__(256) void pv_kernel(
    const unsigned short* __restrict__ pk16,
    const float* __restrict__ el,
    const float* __restrict__ er,
    const float* __restrict__ c,
    const unsigned short* __restrict__ hT,   // 256 x 16384
    float* __restrict__ out)
{
    __shared__ float er_s[1024];
    __shared__ __align__(16) unsigned short pk_s[32 * 64];
    __shared__ __align__(16) unsigned short Hs[256 * 64];   // 32 KB, swizzled
    __shared__ __align__(16) unsigned short Ps[32 * 72];

    const int tid = threadIdx.x;
    const int w = tid >> 6, l = tid & 63;
    const int q = l >> 4, ml = l & 15;
    const int b = blockIdx.y;
    const int i0 = blockIdx.x * 32;

    *(float4*)(er_s + tid * 4) = *(const float4*)(er + (b << 10) + tid * 4);
    *(u16x8*)(pk_s + tid * 8) =
        *(const u16x8*)(pk16 + ((size_t)(b << 10) + i0) * 64 + tid * 8);
    const int ib = tid >> 3;
    const int js = (tid & 7) * 8;
    const float eli_b = el[(b << 10) + i0 + ib];
    const float ci = c[(b << 10) + i0 + ib];
    __syncthreads();

    f32x4 acc[2][4];
    for (int i = 0; i < 2; ++i)
        for (int j = 0; j < 4; ++j) {
            f32x4 z = {0.f, 0.f, 0.f, 0.f};
            acc[i][j] = z;
        }

    const unsigned short* hb = hT + (size_t)b * 1024;

    for (int j0 = 0; j0 < 1024; j0 += 64) {
        for (int cr = 0; cr < 8; ++cr) {
            const int cb = cr * 256 + (w << 6);
            const int p = cb + l;
            const int r = p >> 3;
            const int cc = (p & 7) ^ (r & 7);
            gload_lds16(hb + (size_t)r * 16384 + j0 + cc * 8, Hs + cb * 8);
        }
        {
            const unsigned hw = pk_s[ib * 64 + ((j0 + js) >> 4)];
            const unsigned v = (hw >> ((j0 + js) & 15)) & 0xFFu;
            u16x8 pvv;
#pragma unroll
            for (int u = 0; u < 8; ++u) {
                float e = eli_b + er_s[j0 + js + u];
                e = e > 0.f ? e : ALPHA * e;
                const float p = ((v >> u) & 1u) ? __expf(e - ci) : 0.f;
                pvv[u] = f2bf(p);
            }
            *(u16x8*)(Ps + ib * 72 + js) = pvv;
        }
        __syncthreads();

        bf16x8 aF[2][2], bF[2][4];
#pragma unroll
        for (int ks = 0; ks < 2; ++ks) {
#pragma unroll
            for (int mt = 0; mt < 2; ++mt)
                aF[ks][mt] = *(const bf16x8*)(Ps + (mt * 16 + ml) * 72 + ks * 32 + q * 8);
#pragma unroll
            for (int nt = 0; nt < 4; ++nt) {
                const int oc = (w << 6) + nt * 16 + ml;
                bF[ks][nt] = *(const bf16x8*)(Hs + (oc * 8 + ((ks * 4 + q) ^ (oc & 7))) * 8);
            }
        }
#pragma unroll
        for (int ks = 0; ks < 2; ++ks)
            for (int mt = 0; mt < 2; ++mt)
                for (int nt = 0; nt < 4; ++nt)
                    acc[mt][nt] = __builtin_amdgcn_mfma_f32_16x16x32_bf16(
                        aF[ks][mt], bF[ks][nt], acc[mt][nt], 0, 0, 0);
        __syncthreads();
    }

    float* ob = out + (size_t)b * 262144;
    for (int mt = 0; mt < 2; ++mt)
        for (int nt = 0; nt < 4; ++nt) {
            const int gn = (w << 6) + nt * 16 + ml;
            for (int r = 0; r < 4; ++r) {
                const int gm = i0 + mt * 16 + q * 4 + r;
                ob[(size_t)gm * 256 + gn] = acc[mt][nt][r];
            }
        }
}

// ---------------------------------------------------------------------------
// Workspace (~10.8 MB):
//   Wtbf (bf16) @ 0       : 131072
//   wa   (f32)  @ 131072  : 2048
//   h_T  (bf16) @ 133120  : 8388608   (256 x 16384)
//   el   (f32)  @ 8521728 : 65536
//   er   (f32)  @ 8587264 : 65536
//   c    (f32)  @ 8652800 : 65536
//   pk16 (u16)  @ 8718336 : 2097152
// ---------------------------------------------------------------------------
extern "C" void kernel_launch(void* const* d_in, const int* in_sizes, int n_in,
                              void* d_out, int out_size, void* d_ws, size_t ws_size,
                              hipStream_t stream) {
    const float* x   = (const float*)d_in[0];   // (16,1024,256) fp32
    const int*   adj = (const int*)d_in[1];     // (16,1024,1024) int32
    const float* W   = (const float*)d_in[2];   // (256,256) fp32
    const float* a   = (const float*)d_in[3];   // (512,1) fp32
    float* out = (float*)d_out;                 // (16,1024,256) fp32

    char* ws = (char*)d_ws;
    unsigned short* Wtbf = (unsigned short*)(ws);
    float* wa            = (float*)(ws + 131072);
    unsigned short* h_T  = (unsigned short*)(ws + 133120);
    float* el            = (float*)(ws + 8521728);
    float* er            = (float*)(ws + 8587264);
    float* c             = (float*)(ws + 8652800);
    unsigned short* pk16 = (unsigned short*)(ws + 8718336);

    wt_wa_kernel<<<dim3(257), dim3(256), 0, stream>>>(W, a, Wtbf, wa);

    // h_T = Wtbf @ x^T (direct fp32 x), fused exact el/er
    gemm_hx<<<dim3(128, 4), dim3(256), 0, stream>>>(Wtbf, x, wa, h_T, el, er);

    mask_kernel<<<dim3(4096), dim3(256), 0, stream>>>(adj, el, er, c, pk16);

    pv_kernel<<<dim3(32, 16), dim3(256), 0, stream>>>(pk16, el, er, c, h_T, out);
}

// Round 11
// 155.144 us; speedup vs baseline: 1.0642x; 1.0642x over previous
//
#include <hip/hip_runtime.h>
#include <stdint.h>

#define ALPHA 0.2f

typedef __attribute__((ext_vector_type(8))) short bf16x8;
typedef __attribute__((ext_vector_type(8))) unsigned short u16x8;
typedef __attribute__((ext_vector_type(4))) float f32x4;

__device__ __forceinline__ unsigned short f2bf(float f) {
    unsigned int u = __float_as_uint(f);
    u += 0x7fffu + ((u >> 16) & 1u);   // RNE
    return (unsigned short)(u >> 16);
}

__device__ __forceinline__ void gload_lds16(const void* g, void* l) {
    __builtin_amdgcn_global_load_lds(
        (const __attribute__((address_space(1))) unsigned int*)g,
        (__attribute__((address_space(3))) unsigned int*)l, 16, 0, 0);
}

// ---------------------------------------------------------------------------
// Blocks 0..255: Wtbf[o*256+t] = bf16(W[t*256+o]).
// Block 256:     wa[k] = W[k,:]·a_l ; wa[256+k] = W[k,:]·a_r  (fp32).
// ---------------------------------------------------------------------------
__global__ void wt_wa_kernel(const float* __restrict__ W,
                             const float* __restrict__ a,
                             unsigned short* __restrict__ Wtbf,
                             float* __restrict__ wa) {
    const int t = threadIdx.x;
    if (blockIdx.x < 256) {
        const int o = blockIdx.x;
        Wtbf[o * 256 + t] = f2bf(W[t * 256 + o]);
    } else {
        float sl = 0.f, sr = 0.f;
        const float* wr = W + t * 256;
        for (int o = 0; o < 256; ++o) {
            const float wv = wr[o];
            sl += wv * a[o];
            sr += wv * a[256 + o];
        }
        wa[t] = sl;
        wa[256 + t] = sr;
    }
}

// ---------------------------------------------------------------------------
// One wave per row r: el[r] = x[r,:]·wa_l, er[r] = x[r,:]·wa_r,
// and xbf[r,:] = bf16(x[r,:]).  (R8-verified; x read ONCE here)
// ---------------------------------------------------------------------------
__global__ __launch_bounds__(256) void eler2x_kernel(
    const float* __restrict__ x, const float* __restrict__ wa,
    float* __restrict__ el, float* __restrict__ er,
    unsigned short* __restrict__ xbf)
{
    const int w = threadIdx.x >> 6, l = threadIdx.x & 63;
    const int r = blockIdx.x * 4 + w;       // 0..16383
    const float4 xv = *(const float4*)(x + (size_t)r * 256 + l * 4);
    const float4 al = *(const float4*)(wa + l * 4);
    const float4 ar = *(const float4*)(wa + 256 + l * 4);

    ushort4 xb;
    xb.x = f2bf(xv.x); xb.y = f2bf(xv.y); xb.z = f2bf(xv.z); xb.w = f2bf(xv.w);
    *(ushort4*)(xbf + (size_t)r * 256 + l * 4) = xb;

    float sl = xv.x * al.x + xv.y * al.y + xv.z * al.z + xv.w * al.w;
    float sr = xv.x * ar.x + xv.y * ar.y + xv.z * ar.z + xv.w * ar.w;
#pragma unroll
    for (int off = 32; off >= 1; off >>= 1) {
        sl += __shfl_xor(sl, off);
        sr += __shfl_xor(sr, off);
    }
    if (l == 0) { el[r] = sl; er[r] = sr; }
}

// ---------------------------------------------------------------------------
// h_T (256 x 16384) = Wtbf (256x256) @ xbf^T.  (R6-verified)
// 64(m) x 128(n) tiles, K-step 64, grid (128,4) = 512 blocks (2/CU).
// XOR-swizzled LDS; bf16 re-reads of xbf are L2/L3-cheap (8 MB unique).
// ---------------------------------------------------------------------------
__global__ __launch_bounds__(256) void gemm_h(
    const unsigned short* __restrict__ A,    // Wtbf 256x256
    const unsigned short* __restrict__ Bt,   // xbf 16384x256
    unsigned short* __restrict__ C)          // h_T 256x16384
{
    __shared__ __align__(16) unsigned short As[64 * 64];    //  8 KB
    __shared__ __align__(16) unsigned short Bs[128 * 64];   // 16 KB

    const int tid = threadIdx.x;
    const int w = tid >> 6, l = tid & 63;
    const int q = l >> 4, ml = l & 15;
    const int wm = (w >> 1) * 32;
    const int wn = (w & 1) * 64;
    const int m0 = blockIdx.y * 64;
    const int n0 = blockIdx.x * 128;

    f32x4 acc[2][4];
    for (int i = 0; i < 2; ++i)
        for (int j = 0; j < 4; ++j) {
            f32x4 z = {0.f, 0.f, 0.f, 0.f};
            acc[i][j] = z;
        }

    for (int k0 = 0; k0 < 256; k0 += 64) {
        for (int c = 0; c < 2; ++c) {
            const int cb = c * 256 + (w << 6);
            const int p = cb + l;
            const int r = p >> 3;
            const int cc = (p & 7) ^ (r & 7);
            gload_lds16(A + (size_t)(m0 + r) * 256 + k0 + cc * 8, As + cb * 8);
        }
        for (int c = 0; c < 4; ++c) {
            const int cb = c * 256 + (w << 6);
            const int p = cb + l;
            const int r = p >> 3;
            const int cc = (p & 7) ^ (r & 7);
            gload_lds16(Bt + (size_t)(n0 + r) * 256 + k0 + cc * 8, Bs + cb * 8);
        }
        __syncthreads();

        bf16x8 aF[2][2], bF[2][4];
#pragma unroll
        for (int ks = 0; ks < 2; ++ks) {
#pragma unroll
            for (int mt = 0; mt < 2; ++mt) {
                const int mm = wm + mt * 16 + ml;
                aF[ks][mt] = *(const bf16x8*)(As + (mm * 8 + ((ks * 4 + q) ^ (mm & 7))) * 8);
            }
#pragma unroll
            for (int nt = 0; nt < 4; ++nt) {
                const int nn = wn + nt * 16 + ml;
                bF[ks][nt] = *(const bf16x8*)(Bs + (nn * 8 + ((ks * 4 + q) ^ (nn & 7))) * 8);
            }
        }
#pragma unroll
        for (int ks = 0; ks < 2; ++ks)
            for (int mt = 0; mt < 2; ++mt)
                for (int nt = 0; nt < 4; ++nt)
                    acc[mt][nt] = __builtin_amdgcn_mfma_f32_16x16x32_bf16(
                        aF[ks][mt], bF[ks][nt], acc[mt][nt], 0, 0, 0);
        __syncthreads();
    }

    for (int mt = 0; mt < 2; ++mt)
        for (int nt = 0; nt < 4; ++nt) {
            const int gn = n0 + wn + nt * 16 + ml;
            for (int r = 0; r < 4; ++r) {
                const int gm = m0 + wm + mt * 16 + q * 4 + r;
                C[(size_t)gm * 16384 + gn] = f2bf(acc[mt][nt][r]);
            }
        }
}

// ---------------------------------------------------------------------------
// Mask pre-pass (R8-verified): one wave per row, 4096 blocks, ONLINE sum
// (no max pass — logits tiny by construction; exp can't overflow in fp32).
// c[row] = log( sum_j adj ? exp(leakyrelu(el_i+er_j)) : 0 ).
// Adjacency packed to pk16[row*64 + l] (bit t <-> j = 16*l + t).
// ---------------------------------------------------------------------------
__global__ __launch_bounds__(256) void mask_kernel(
    const int* __restrict__ adj,
    const float* __restrict__ el,
    const float* __restrict__ er,
    float* __restrict__ c,
    unsigned short* __restrict__ pk16)
{
    __shared__ unsigned char nibs[4][256];

    const int w = threadIdx.x >> 6, l = threadIdx.x & 63;
    const int row = blockIdx.x * 4 + w;       // 0..16383
    const int b = row >> 10;
    const int* arow = adj + (size_t)row * 1024;
    const float* erb = er + (b << 10);
    const float eli = el[row];

    int4 av[4]; float4 erv[4];
#pragma unroll
    for (int it = 0; it < 4; ++it) {
        const int j = it * 256 + l * 4;
        av[it]  = *(const int4*)(arow + j);
        erv[it] = *(const float4*)(erb + j);
    }

    const float NINF = -__builtin_inff();
    float s = 0.f;
#pragma unroll
    for (int it = 0; it < 4; ++it) {
        float e0 = eli + erv[it].x; e0 = e0 > 0.f ? e0 : ALPHA * e0;
        float e1 = eli + erv[it].y; e1 = e1 > 0.f ? e1 : ALPHA * e1;
        float e2 = eli + erv[it].z; e2 = e2 > 0.f ? e2 : ALPHA * e2;
        float e3 = eli + erv[it].w; e3 = e3 > 0.f ? e3 : ALPHA * e3;
        e0 = av[it].x > 0 ? e0 : NINF;   // exp(-inf) = 0
        e1 = av[it].y > 0 ? e1 : NINF;
        e2 = av[it].z > 0 ? e2 : NINF;
        e3 = av[it].w > 0 ? e3 : NINF;
        s += __expf(e0) + __expf(e1) + __expf(e2) + __expf(e3);
        nibs[w][it * 64 + l] =
            (unsigned char)((av[it].x > 0) | ((av[it].y > 0) << 1) |
                            ((av[it].z > 0) << 2) | ((av[it].w > 0) << 3));
    }
#pragma unroll
    for (int off = 32; off >= 1; off >>= 1) s += __shfl_xor(s, off);
    if (l == 0) c[row] = __logf(s);

    const unsigned nr = *(const unsigned int*)(&nibs[w][l * 4]);
    const unsigned short mask16 =
        (unsigned short)((nr & 0xFu) | ((nr >> 4) & 0xF0u) |
                         ((nr >> 8) & 0xF00u) | ((nr >> 12) & 0xF000u));
    pk16[(size_t)row * 64 + l] = mask16;
}

// ---------------------------------------------------------------------------
// PV, 64-row tiles at 512 threads: out[b, i0..i0+63, :] = P @ h[b].
// Grid (16,16) = 256 blocks, 8 waves each (2 m-halves x 4 o-quadrants).
// Halves h_T re-read traffic vs 32-row tiles (16 tile-blocks/batch vs 32);
// P-rebuild still amortized across all waves (8 exps/thread/iter).
// j-step 64; Hs XOR-swizzled (R6-proven pattern); Ps stride 72.
// LDS ~55 KB.
// ---------------------------------------------------------------------------
__global__ __launch_bounds__(512) void pv_kernel(
    const unsigned short* __restrict__ pk16,
    const float* __restrict__ el,
    const float* __restrict__ er,
    const float* __restrict__ c,
    const unsigned short* __restrict__ hT,   // 256 x 16384
    float* __restrict__ out)
{
    __shared__ float er_s[1024];                            //  4 KB
    __shared__ float el_s[64];
    __shared__ float c_s[64];
    __shared__ __align__(16) unsigned short pk_s[64 * 64];  //  8 KB
    __shared__ __align__(16) unsigned short Hs[256 * 64];   // 32 KB, swizzled
    __shared__ __align__(16) unsigned short Ps[64 * 72];    //  9 KB

    const int tid = threadIdx.x;
    const int w = tid >> 6, l = tid & 63;     // w: 0..7
    const int q = l >> 4, ml = l & 15;
    const int wm = (w >> 2) * 32;             // m-half
    const int wn = (w & 3) * 64;              // o-quadrant
    const int b = blockIdx.y;
    const int i0 = blockIdx.x * 64;

    *(float2*)(er_s + tid * 2) = *(const float2*)(er + (b << 10) + tid * 2);
    *(u16x8*)(pk_s + tid * 8) =
        *(const u16x8*)(pk16 + ((size_t)((b << 10) + i0)) * 64 + tid * 8);
    if (tid < 64) {
        el_s[tid] = el[(b << 10) + i0 + tid];
        c_s[tid]  = c[(b << 10) + i0 + tid];
    }
    __syncthreads();

    const int ib = tid >> 3;              // P-row this thread rebuilds (0..63)
    const int js = (tid & 7) * 8;         // j-offset within 64-chunk
    const float eli_b = el_s[ib];
    const float ci = c_s[ib];

    f32x4 acc[2][4];
    for (int i = 0; i < 2; ++i)
        for (int j = 0; j < 4; ++j) {
            f32x4 z = {0.f, 0.f, 0.f, 0.f};
            acc[i][j] = z;
        }

    const unsigned short* hb = hT + (size_t)b * 1024;

    for (int j0 = 0; j0 < 1024; j0 += 64) {
        // stage Hs: 256 rows x 8 chunks = 2048 chunks, 4 rounds x 512 thr
        for (int cr = 0; cr < 4; ++cr) {
            const int cb = cr * 512 + (w << 6);
            const int p = cb + l;
            const int r = p >> 3;
            const int cc = (p & 7) ^ (r & 7);
            gload_lds16(hb + (size_t)r * 16384 + j0 + cc * 8, Hs + cb * 8);
        }
        // rebuild P tile (64 x 64) while loads fly
        {
            const unsigned hw = pk_s[ib * 64 + ((j0 + js) >> 4)];
            const unsigned v = (hw >> ((j0 + js) & 15)) & 0xFFu;  // shift 0 or 8
            u16x8 pvv;
#pragma unroll
            for (int u = 0; u < 8; ++u) {
                float e = eli_b + er_s[j0 + js + u];
                e = e > 0.f ? e : ALPHA * e;
                const float p = ((v >> u) & 1u) ? __expf(e - ci) : 0.f;
                pvv[u] = f2bf(p);
            }
            *(u16x8*)(Ps + ib * 72 + js) = pvv;
        }
        __syncthreads();

        bf16x8 aF[2][2], bF[2][4];
#pragma unroll
        for (int ks = 0; ks < 2; ++ks) {
#pragma unroll
            for (int mt = 0; mt < 2; ++mt)
                aF[ks][mt] = *(const bf16x8*)(Ps + (wm + mt * 16 + ml) * 72 + ks * 32 + q * 8);
#pragma unroll
            for (int nt = 0; nt < 4; ++nt) {
                const int oc = wn + nt * 16 + ml;
                bF[ks][nt] = *(const bf16x8*)(Hs + (oc * 8 + ((ks * 4 + q) ^ (oc & 7))) * 8);
            }
        }
#pragma unroll
        for (int ks = 0; ks < 2; ++ks)
            for (int mt = 0; mt < 2; ++mt)
                for (int nt = 0; nt < 4; ++nt)
                    acc[mt][nt] = __builtin_amdgcn_mfma_f32_16x16x32_bf16(
                        aF[ks][mt], bF[ks][nt], acc[mt][nt], 0, 0, 0);
        __syncthreads();
    }

    float* ob = out + (size_t)b * 262144;
    for (int mt = 0; mt < 2; ++mt)
        for (int nt = 0; nt < 4; ++nt) {
            const int gn = wn + nt * 16 + ml;
            for (int r = 0; r < 4; ++r) {
                const int gm = i0 + wm + mt * 16 + q * 4 + r;
                ob[(size_t)gm * 256 + gn] = acc[mt][nt][r];
            }
        }
}

// ---------------------------------------------------------------------------
// Workspace (~19.2 MB):
//   Wtbf (bf16) @ 0        : 131072
//   wa   (f32)  @ 131072   : 2048
//   xbf  (bf16) @ 133120   : 8388608   (16384 x 256)
//   h_T  (bf16) @ 8521728  : 8388608   (256 x 16384)
//   el   (f32)  @ 16910336 : 65536
//   er   (f32)  @ 16975872 : 65536
//   c    (f32)  @ 17041408 : 65536
//   pk16 (u16)  @ 17106944 : 2097152
// ---------------------------------------------------------------------------
extern "C" void kernel_launch(void* const* d_in, const int* in_sizes, int n_in,
                              void* d_out, int out_size, void* d_ws, size_t ws_size,
                              hipStream_t stream) {
    const float* x   = (const float*)d_in[0];   // (16,1024,256) fp32
    const int*   adj = (const int*)d_in[1];     // (16,1024,1024) int32
    const float* W   = (const float*)d_in[2];   // (256,256) fp32
    const float* a   = (const float*)d_in[3];   // (512,1) fp32
    float* out = (float*)d_out;                 // (16,1024,256) fp32

    char* ws = (char*)d_ws;
    unsigned short* Wtbf  = (unsigned short*)(ws);
    float* wa             = (float*)(ws + 131072);
    unsigned short* xbf   = (unsigned short*)(ws + 133120);
    unsigned short* h_T   = (unsigned short*)(ws + 8521728);
    float* el             = (float*)(ws + 16910336);
    float* er             = (float*)(ws + 16975872);
    float* c              = (float*)(ws + 17041408);
    unsigned short* pk16  = (unsigned short*)(ws + 17106944);

    wt_wa_kernel<<<dim3(257), dim3(256), 0, stream>>>(W, a, Wtbf, wa);

    eler2x_kernel<<<dim3(4096), dim3(256), 0, stream>>>(x, wa, el, er, xbf);

    gemm_h<<<dim3(128, 4), dim3(256), 0, stream>>>(Wtbf, xbf, h_T);

    mask_kernel<<<dim3(4096), dim3(256), 0, stream>>>(adj, el, er, c, pk16);

    pv_kernel<<<dim3(16, 16), dim3(512), 0, stream>>>(pk16, el, er, c, h_T, out);
}